// Round 13
// baseline (196.136 us; speedup 1.0000x reference)
//
#include <hip/hip_runtime.h>
#include <hip/hip_cooperative_groups.h>
#include <math.h>

namespace cg = cooperative_groups;

// Problem constants (from reference setup_inputs)
constexpr int B = 8, N = 2048, H = 512, M = 96, S = 16;
constexpr int E = 256, D = 64, R = 5, MAXD = 600;
constexpr int NZ = 32;            // n-splits for sent max partial
constexpr int NCHUNK = N / NZ;    // 64
constexpr int MT = 8;             // mentions per gemm block
constexpr int HC = 4;             // h-chunks
constexpr int HCH = H / HC;       // 128
constexpr int MT4 = 8;            // m-rows per final-max tile
constexpr int RS = 2 * B * M;     // dotp row-stride (1536 rows)
constexpr float NEG_INF = -1e10f;

constexpr int G_GEMM = 2 * B * (M / MT) * HC;   // 768
constexpr int G_SENT = B * NZ / 2;              // 128
constexpr int G_DIST = MAXD / 4;                // 150
constexpr int P1_ITEMS = G_GEMM + G_SENT + G_DIST;   // 1046

constexpr int G3_PROJ = RS / 4;                 // 384
constexpr int P2_ITEMS = G3_PROJ + B;           // 392
constexpr int P3_ITEMS = (M / MT4) * B;         // 96

__device__ inline void atomicMaxFloat(float* addr, float val) {
    int* ai = (int*)addr;
    int old = *ai;
    while (__int_as_float(old) < val) {
        int assumed = old;
        old = atomicCAS(ai, assumed, __float_as_int(val));
        if (old == assumed) break;
    }
}

// ===========================================================================
// Phase bodies (shared by coop kernel and fallback kernels)
// ===========================================================================
__device__ __forceinline__ void p1_body(
        int item, int t,
        const float* __restrict__ node,
        const int* __restrict__ cmap, const float* __restrict__ cmask,
        const int* __restrict__ dmap, const float* __restrict__ dmask,
        const float* __restrict__ Wc, const float* __restrict__ Wd,
        const float* __restrict__ Wsc, const float* __restrict__ emb,
        float* __restrict__ part, float* __restrict__ dotp,
        float* __restrict__ validAB, float* __restrict__ sD,
        int smap[MT][S], float smask[MT][S], float lp[MT][HCH]) {
    if (item < G_GEMM) {
        int hc   = item & 3;
        int rest = item >> 2;
        int mg = rest % (M / MT);
        int b  = (rest / (M / MT)) % B;
        int z  = rest / ((M / MT) * B);
        const float* W    = z ? Wd : Wc;
        const int*   map  = z ? dmap  : cmap;
        const float* mask = z ? dmask : cmask;

        if (t < MT * S) {
            int mi = t >> 4, s = t & 15;
            size_t off = ((size_t)b * M + mg * MT + mi) * S + s;
            smap[mi][s]  = map[off];
            smask[mi][s] = mask[off];
        }
        __syncthreads();

        {
            int mi = t >> 5, slot = t & 31;
            float4 a = make_float4(0.f, 0.f, 0.f, 0.f);
            #pragma unroll
            for (int s = 0; s < S; ++s) {
                float mk = smask[mi][s];
                const float4 v = reinterpret_cast<const float4*>(
                    node + ((size_t)b * N + smap[mi][s]) * H + hc * HCH)[slot];
                a.x += mk * v.x; a.y += mk * v.y;
                a.z += mk * v.z; a.w += mk * v.w;
            }
            reinterpret_cast<float4*>(&lp[mi][0])[slot] = a;
        }
        if (hc == 0 && t < MT) {
            float ms = 0.f;
            #pragma unroll
            for (int s = 0; s < S; ++s) ms += smask[t][s];
            validAB[((size_t)z * B + b) * M + mg * MT + t] = (ms > 0.f) ? 1.f : 0.f;
        }
        __syncthreads();

        float acc[MT] = {};
        const float* Wp = W + (size_t)(hc * HCH) * E + t;
        #pragma unroll 4
        for (int hh = 0; hh < HCH; hh += 4) {
            float w0 = Wp[(size_t)(hh + 0) * E];
            float w1 = Wp[(size_t)(hh + 1) * E];
            float w2 = Wp[(size_t)(hh + 2) * E];
            float w3 = Wp[(size_t)(hh + 3) * E];
            #pragma unroll
            for (int mi = 0; mi < MT; ++mi) {
                const float4 pv = *reinterpret_cast<const float4*>(&lp[mi][hh]);
                acc[mi] += pv.x * w0 + pv.y * w1 + pv.z * w2 + pv.w * w3;
            }
        }
        #pragma unroll
        for (int mi = 0; mi < MT; ++mi) {
            size_t row = ((size_t)z * B + b) * M + mg * MT + mi;
            dotp[((size_t)hc * RS + row) * E + t] = acc[mi];
        }
    } else if (item < G_GEMM + G_SENT) {
        int sb = item - G_GEMM;
        int b = sb >> 4;
        int z = ((sb & 15) << 1) + (t >> 7);
        int tt = t & 127;
        const float4* p = reinterpret_cast<const float4*>(
            node + ((size_t)b * N + (size_t)z * NCHUNK) * H) + tt;
        float4 mx = p[0];
        #pragma unroll 8
        for (int n = 1; n < NCHUNK; ++n) {
            float4 v = p[(size_t)n * (H / 4)];
            mx.x = fmaxf(mx.x, v.x); mx.y = fmaxf(mx.y, v.y);
            mx.z = fmaxf(mx.z, v.z); mx.w = fmaxf(mx.w, v.w);
        }
        reinterpret_cast<float4*>(part + ((size_t)z * B + b) * H)[tt] = mx;
    } else {
        int d = (item - G_GEMM - G_SENT) * 4 + (t >> 6);
        int k = t & 63;
        float v = emb[(size_t)d * D + k];
        #pragma unroll
        for (int r = 0; r < R; ++r) {
            float p = v * Wsc[(size_t)(2 * E + k) * R + r];
            for (int off = 32; off; off >>= 1) p += __shfl_down(p, off, 64);
            if (k == 0) sD[d * R + r] = p;
        }
    }
}

__device__ __forceinline__ void p2_body(
        int item, int t,
        const float* __restrict__ dotp,
        const float* __restrict__ bc, const float* __restrict__ bd,
        const float* __restrict__ Wsc, const float* __restrict__ bsc,
        const float* __restrict__ part,
        float* __restrict__ sAB, float* __restrict__ sS,
        float sent[H], float red[R][4]) {
    const int wave = t >> 6, lane = t & 63;
    if (item < G3_PROJ) {
        int rid = item * 4 + wave;
        int z = rid / (B * M);
        const float* bias = z ? bd : bc;
        int scoff = z ? E : 0;

        float4 dv = reinterpret_cast<const float4*>(bias)[lane];
        #pragma unroll
        for (int hc = 0; hc < HC; ++hc) {
            const float4 v = reinterpret_cast<const float4*>(
                dotp + ((size_t)hc * RS + rid) * E)[lane];
            dv.x += v.x; dv.y += v.y; dv.z += v.z; dv.w += v.w;
        }
        float v0 = tanhf(dv.x), v1 = tanhf(dv.y), v2 = tanhf(dv.z), v3 = tanhf(dv.w);

        int e0 = scoff + 4 * lane;
        float p[R];
        #pragma unroll
        for (int r = 0; r < R; ++r) {
            p[r] = v0 * Wsc[(size_t)(e0 + 0) * R + r] + v1 * Wsc[(size_t)(e0 + 1) * R + r]
                 + v2 * Wsc[(size_t)(e0 + 2) * R + r] + v3 * Wsc[(size_t)(e0 + 3) * R + r];
        }
        #pragma unroll
        for (int r = 0; r < R; ++r) {
            for (int off = 32; off; off >>= 1) p[r] += __shfl_down(p[r], off, 64);
        }
        if (lane == 0) {
            #pragma unroll
            for (int r = 0; r < R; ++r) sAB[(size_t)rid * R + r] = p[r];
        }
    } else {
        int b = item - G3_PROJ;
        for (int h = t; h < H; h += 256) {
            float mx = -INFINITY;
            #pragma unroll 8
            for (int z = 0; z < NZ; ++z) mx = fmaxf(mx, part[((size_t)z * B + b) * H + h]);
            sent[h] = mx;
        }
        __syncthreads();
        float acc[R] = {};
        for (int h = t; h < H; h += 256) {
            float v = sent[h];
            const float* w = Wsc + (size_t)(2 * E + D + h) * R;
            #pragma unroll
            for (int r = 0; r < R; ++r) acc[r] += v * w[r];
        }
        #pragma unroll
        for (int r = 0; r < R; ++r) {
            float v = acc[r];
            for (int off = 32; off; off >>= 1) v += __shfl_down(v, off, 64);
            if (lane == 0) red[r][wave] = v;
        }
        __syncthreads();
        if (t < R) sS[b * R + t] = red[t][0] + red[t][1] + red[t][2] + red[t][3] + bsc[t];
    }
}

__device__ __forceinline__ void p3_body(
        int item, int t,
        const int* __restrict__ distance,
        const float* __restrict__ sAB, const float* __restrict__ validAB,
        const float* __restrict__ sD, const float* __restrict__ sS,
        float* __restrict__ out,
        float lB[M * R], float lD[MAXD * R], float lA[MT4 * R],
        float lvA[MT4], float lvB[M], float red[R][4]) {
    const int g = item % (M / MT4);
    const int b = item / (M / MT4);
    const int wave = t >> 6, lane = t & 63;

    for (int i = t; i < M * R; i += 256) lB[i] = sAB[((size_t)(B + b)) * M * R + i];
    for (int i = t; i < MAXD * R; i += 256) lD[i] = sD[i];
    if (t < MT4 * R) lA[t] = sAB[((size_t)b * M + g * MT4) * R + t] + sS[b * R + (t % R)];
    if (t < MT4) lvA[t] = validAB[(size_t)b * M + g * MT4 + t];
    for (int i = t; i < M; i += 256) lvB[i] = validAB[((size_t)B + b) * M + i];
    __syncthreads();

    float mx[R];
    #pragma unroll
    for (int r = 0; r < R; ++r) mx[r] = NEG_INF;

    #pragma unroll
    for (int it = 0; it < (MT4 * M) / 256; ++it) {
        int idx = it * 256 + t;
        int mi = idx / M, n = idx % M;
        int dist = distance[((size_t)b * M + g * MT4 + mi) * M + n];
        if (lvA[mi] > 0.f && lvB[n] > 0.f && dist >= 0 /*DIST_THRESH*/) {
            #pragma unroll
            for (int r = 0; r < R; ++r)
                mx[r] = fmaxf(mx[r], lA[mi * R + r] + lB[n * R + r] + lD[dist * R + r]);
        }
    }
    #pragma unroll
    for (int r = 0; r < R; ++r) {
        float v = mx[r];
        for (int off = 32; off; off >>= 1) v = fmaxf(v, __shfl_down(v, off, 64));
        if (lane == 0) red[r][wave] = v;
    }
    __syncthreads();
    if (t < R) {
        float v = fmaxf(fmaxf(red[t][0], red[t][1]), fmaxf(red[t][2], red[t][3]));
        atomicMaxFloat(out + b * R + t, v);
    }
}

// ===========================================================================
// Cooperative single-dispatch kernel
// ===========================================================================
__global__ __launch_bounds__(256, 4)
void k_coop(const float* __restrict__ node,
            const int* __restrict__ cmap, const float* __restrict__ cmask,
            const int* __restrict__ dmap, const float* __restrict__ dmask,
            const int* __restrict__ distance,
            const float* __restrict__ Wc, const float* __restrict__ bc,
            const float* __restrict__ Wd, const float* __restrict__ bd,
            const float* __restrict__ Wsc, const float* __restrict__ bsc,
            const float* __restrict__ emb,
            float* __restrict__ part, float* __restrict__ dotp,
            float* __restrict__ validAB, float* __restrict__ sD,
            float* __restrict__ sAB, float* __restrict__ sS,
            float* __restrict__ out) {
    cg::grid_group grid = cg::this_grid();
    const int t = threadIdx.x;
    const int blk = blockIdx.x;
    const int GD = gridDim.x;

    __shared__ int   smap[MT][S];
    __shared__ float smask[MT][S];
    __shared__ float lp[MT][HCH];
    __shared__ float sent[H];
    __shared__ float red[R][4];
    __shared__ float lB[M * R];
    __shared__ float lD[MAXD * R];
    __shared__ float lA[MT4 * R];
    __shared__ float lvA[MT4], lvB[M];

    if (blk == 0 && t < B * R) out[t] = NEG_INF;

    for (int item = blk; item < P1_ITEMS; item += GD) {
        __syncthreads();
        p1_body(item, t, node, cmap, cmask, dmap, dmask, Wc, Wd, Wsc, emb,
                part, dotp, validAB, sD, smap, smask, lp);
    }
    grid.sync();
    for (int item = blk; item < P2_ITEMS; item += GD) {
        __syncthreads();
        p2_body(item, t, dotp, bc, bd, Wsc, bsc, part, sAB, sS, sent, red);
    }
    grid.sync();
    for (int item = blk; item < P3_ITEMS; item += GD) {
        __syncthreads();
        p3_body(item, t, distance, sAB, validAB, sD, sS, out,
                lB, lD, lA, lvA, lvB, red);
    }
}

// ===========================================================================
// Fallback: validated round-12 3-kernel pipeline (50.5 us)
// ===========================================================================
__global__ __launch_bounds__(256)
void k1(const float* __restrict__ node,
        const int* __restrict__ cmap, const float* __restrict__ cmask,
        const int* __restrict__ dmap, const float* __restrict__ dmask,
        const float* __restrict__ Wc, const float* __restrict__ Wd,
        const float* __restrict__ Wsc, const float* __restrict__ emb,
        float* __restrict__ part, float* __restrict__ dotp,
        float* __restrict__ validAB, float* __restrict__ sD,
        float* __restrict__ out) {
    __shared__ int   smap[MT][S];
    __shared__ float smask[MT][S];
    __shared__ float lp[MT][HCH];
    if (blockIdx.x == 0 && threadIdx.x < B * R) out[threadIdx.x] = NEG_INF;
    p1_body(blockIdx.x, threadIdx.x, node, cmap, cmask, dmap, dmask, Wc, Wd, Wsc, emb,
            part, dotp, validAB, sD, smap, smask, lp);
}

__global__ __launch_bounds__(256)
void k3(const float* __restrict__ dotp,
        const float* __restrict__ bc, const float* __restrict__ bd,
        const float* __restrict__ Wsc, const float* __restrict__ bsc,
        const float* __restrict__ part,
        float* __restrict__ sAB, float* __restrict__ sS) {
    __shared__ float sent[H];
    __shared__ float red[R][4];
    p2_body(blockIdx.x, threadIdx.x, dotp, bc, bd, Wsc, bsc, part, sAB, sS, sent, red);
}

__global__ __launch_bounds__(256)
void k4(const int* __restrict__ distance,
        const float* __restrict__ sAB, const float* __restrict__ validAB,
        const float* __restrict__ sD, const float* __restrict__ sS,
        float* __restrict__ out) {
    __shared__ float lB[M * R];
    __shared__ float lD[MAXD * R];
    __shared__ float lA[MT4 * R];
    __shared__ float lvA[MT4], lvB[M];
    __shared__ float red[R][4];
    p3_body(blockIdx.x, threadIdx.x, distance, sAB, validAB, sD, sS, out,
            lB, lD, lA, lvA, lvB, red);
}

// ---------------------------------------------------------------------------
extern "C" void kernel_launch(void* const* d_in, const int* in_sizes, int n_in,
                              void* d_out, int out_size, void* d_ws, size_t ws_size,
                              hipStream_t stream) {
    const float* node     = (const float*)d_in[0];
    const int*   cmap     = (const int*)  d_in[1];
    const float* cmask    = (const float*)d_in[2];
    const int*   dmap     = (const int*)  d_in[3];
    const float* dmask    = (const float*)d_in[4];
    const int*   distance = (const int*)  d_in[5];
    const float* Wc       = (const float*)d_in[6];
    const float* bc       = (const float*)d_in[7];
    const float* Wd       = (const float*)d_in[8];
    const float* bd       = (const float*)d_in[9];
    const float* Wsc      = (const float*)d_in[10];
    const float* bsc      = (const float*)d_in[11];
    const float* emb      = (const float*)d_in[12];
    float* out = (float*)d_out;

    // workspace layout (floats): total ~7 MB
    float* ws      = (float*)d_ws;
    float* part    = ws;                             // NZ*B*H      = 131072
    float* validAB = part + (size_t)NZ * B * H;      // 2*B*M       = 1536
    float* sD      = validAB + 2 * B * M;            // MAXD*R      = 3000
    float* sS      = sD + MAXD * R;                  // B*R         = 40
    float* sAB     = sS + B * R;                     // RS*R        = 7680
    float* dotp    = sAB + (size_t)RS * R;           // HC*RS*E     = 1572864

    int occ = 0;
    hipError_t qerr = hipOccupancyMaxActiveBlocksPerMultiprocessor(&occ, k_coop, 256, 0);
    int grid = occ * 256;
    if (grid > 1024) grid = 1024;

    hipError_t lerr = hipErrorUnknown;
    if (qerr == hipSuccess && grid >= 128) {
        void* args[] = {
            (void*)&node, (void*)&cmap, (void*)&cmask, (void*)&dmap, (void*)&dmask,
            (void*)&distance, (void*)&Wc, (void*)&bc, (void*)&Wd, (void*)&bd,
            (void*)&Wsc, (void*)&bsc, (void*)&emb,
            (void*)&part, (void*)&dotp, (void*)&validAB, (void*)&sD,
            (void*)&sAB, (void*)&sS, (void*)&out
        };
        lerr = hipLaunchCooperativeKernel((void*)k_coop, dim3(grid), dim3(256), args, 0, stream);
    }
    if (lerr != hipSuccess) {
        hipLaunchKernelGGL(k1, dim3(P1_ITEMS), dim3(256), 0, stream,
                           node, cmap, cmask, dmap, dmask, Wc, Wd, Wsc, emb,
                           part, dotp, validAB, sD, out);
        hipLaunchKernelGGL(k3, dim3(P2_ITEMS), dim3(256), 0, stream,
                           dotp, bc, bd, Wsc, bsc, part, sAB, sS);
        hipLaunchKernelGGL(k4, dim3(P3_ITEMS), dim3(256), 0, stream,
                           distance, sAB, validAB, sD, sS, out);
    }
}

// Round 14
// 62.800 us; speedup vs baseline: 3.1232x; 3.1232x over previous
//
#include <hip/hip_runtime.h>
#include <math.h>

// Problem constants (from reference setup_inputs)
constexpr int B = 8, N = 2048, H = 512, M = 96, S = 16;
constexpr int E = 256, D = 64, R = 5, MAXD = 600;
constexpr int NZ = 32;            // n-splits for sent max partial
constexpr int NCHUNK = N / NZ;    // 64
constexpr int MT = 4;             // mentions per entity block (= waves)
constexpr int HC = 4;             // h-chunks (= waves)
constexpr int HCH = H / HC;       // 128
constexpr int MT4 = 8;            // m-rows per final-max tile
constexpr float NEG_INF = -1e10f;

constexpr int X_GEMM = 2 * B * (M / MT);        // 384 fused entity blocks
constexpr int X_SENT = B * NZ / 2;              // 128 sent-partial blocks (2 z each)
constexpr int X_DIST = MAXD / 4;                // 150
constexpr int XG = X_GEMM + X_SENT + X_DIST;    // 662

__device__ inline void atomicMaxFloat(float* addr, float val) {
    int* ai = (int*)addr;
    int old = *ai;
    while (__int_as_float(old) < val) {
        int assumed = old;
        old = atomicCAS(ai, assumed, __float_as_int(val));
        if (old == assumed) break;
    }
}

// ===========================================================================
// kX: fused entity pipeline (pool-slice | partial-GEMM | sum+tanh+proj all in
//     one block, wave = h-chunk) | sent-partial | dist table | out init
// ===========================================================================
__global__ __launch_bounds__(256)
void kX(const float* __restrict__ node,
        const int* __restrict__ cmap, const float* __restrict__ cmask,
        const int* __restrict__ dmap, const float* __restrict__ dmask,
        const float* __restrict__ Wc, const float* __restrict__ bc,
        const float* __restrict__ Wd, const float* __restrict__ bd,
        const float* __restrict__ Wsc, const float* __restrict__ emb,
        float* __restrict__ part, float* __restrict__ sAB,
        float* __restrict__ validAB, float* __restrict__ sD,
        float* __restrict__ out) {
    const int blk = blockIdx.x;
    const int t = threadIdx.x;
    const int wave = t >> 6, lane = t & 63;

    if (blk == 0 && t < B * R) out[t] = NEG_INF;   // init for kY's atomicMax

    if (blk < X_GEMM) {
        // block = (z, b, mg): 4 mentions, wave = h-chunk of 128
        int mg = blk % (M / MT);
        int b  = (blk / (M / MT)) % B;
        int z  = blk / ((M / MT) * B);
        const float* W    = z ? Wd : Wc;
        const float* bias = z ? bd : bc;
        const int*   map  = z ? dmap  : cmap;
        const float* mask = z ? dmask : cmask;
        int scoff = z ? E : 0;

        __shared__ int   smap[MT][S];
        __shared__ float smask[MT][S];
        __shared__ float pool[HC][MT][HCH];    // 8 KB
        __shared__ float red4[HC][MT][E];      // 16 KB

        if (t < MT * S) {
            int mi = t >> 4, s = t & 15;
            size_t off = ((size_t)b * M + mg * MT + mi) * S + s;
            smap[mi][s]  = map[off];
            smask[mi][s] = mask[off];
        }
        __syncthreads();

        // pool: wave = h-chunk; 64 lanes cover 4 mentions x 32 float4-slots (2 items)
        {
            const int hc = wave;
            #pragma unroll
            for (int it = 0; it < 2; ++it) {
                int item = it * 64 + lane;          // [0,128)
                int mi = item >> 5, slot = item & 31;
                float4 a = make_float4(0.f, 0.f, 0.f, 0.f);
                #pragma unroll
                for (int s = 0; s < S; ++s) {
                    float mk = smask[mi][s];
                    const float4 v = reinterpret_cast<const float4*>(
                        node + ((size_t)b * N + smap[mi][s]) * H + hc * HCH)[slot];
                    a.x += mk * v.x; a.y += mk * v.y;
                    a.z += mk * v.z; a.w += mk * v.w;
                }
                reinterpret_cast<float4*>(&pool[hc][mi][0])[slot] = a;
            }
        }
        if (t < MT) {
            float ms = 0.f;
            #pragma unroll
            for (int s = 0; s < S; ++s) ms += smask[t][s];
            validAB[((size_t)z * B + b) * M + mg * MT + t] = (ms > 0.f) ? 1.f : 0.f;
        }
        __syncthreads();

        // partial GEMM: wave = h-chunk, lane = e-quad; 4 mentions in regs
        {
            const int hc = wave;
            const float4* W4 = reinterpret_cast<const float4*>(W) + lane;
            float4 a0 = make_float4(0.f, 0.f, 0.f, 0.f);
            float4 a1 = a0, a2 = a0, a3 = a0;
            #pragma unroll 4
            for (int hh4 = 0; hh4 < HCH / 4; ++hh4) {   // 32 iters of 4 h's
                int h = hh4 * 4;
                const float4 w0 = W4[(size_t)(hc * HCH + h + 0) * (E / 4)];
                const float4 w1 = W4[(size_t)(hc * HCH + h + 1) * (E / 4)];
                const float4 w2 = W4[(size_t)(hc * HCH + h + 2) * (E / 4)];
                const float4 w3 = W4[(size_t)(hc * HCH + h + 3) * (E / 4)];
                const float4 p0 = *reinterpret_cast<const float4*>(&pool[hc][0][h]);
                const float4 p1 = *reinterpret_cast<const float4*>(&pool[hc][1][h]);
                const float4 p2 = *reinterpret_cast<const float4*>(&pool[hc][2][h]);
                const float4 p3 = *reinterpret_cast<const float4*>(&pool[hc][3][h]);
                a0.x += p0.x*w0.x + p0.y*w1.x + p0.z*w2.x + p0.w*w3.x;
                a0.y += p0.x*w0.y + p0.y*w1.y + p0.z*w2.y + p0.w*w3.y;
                a0.z += p0.x*w0.z + p0.y*w1.z + p0.z*w2.z + p0.w*w3.z;
                a0.w += p0.x*w0.w + p0.y*w1.w + p0.z*w2.w + p0.w*w3.w;
                a1.x += p1.x*w0.x + p1.y*w1.x + p1.z*w2.x + p1.w*w3.x;
                a1.y += p1.x*w0.y + p1.y*w1.y + p1.z*w2.y + p1.w*w3.y;
                a1.z += p1.x*w0.z + p1.y*w1.z + p1.z*w2.z + p1.w*w3.z;
                a1.w += p1.x*w0.w + p1.y*w1.w + p1.z*w2.w + p1.w*w3.w;
                a2.x += p2.x*w0.x + p2.y*w1.x + p2.z*w2.x + p2.w*w3.x;
                a2.y += p2.x*w0.y + p2.y*w1.y + p2.z*w2.y + p2.w*w3.y;
                a2.z += p2.x*w0.z + p2.y*w1.z + p2.z*w2.z + p2.w*w3.z;
                a2.w += p2.x*w0.w + p2.y*w1.w + p2.z*w2.w + p2.w*w3.w;
                a3.x += p3.x*w0.x + p3.y*w1.x + p3.z*w2.x + p3.w*w3.x;
                a3.y += p3.x*w0.y + p3.y*w1.y + p3.z*w2.y + p3.w*w3.y;
                a3.z += p3.x*w0.z + p3.y*w1.z + p3.z*w2.z + p3.w*w3.z;
                a3.w += p3.x*w0.w + p3.y*w1.w + p3.z*w2.w + p3.w*w3.w;
            }
            reinterpret_cast<float4*>(&red4[hc][0][0])[lane] = a0;
            reinterpret_cast<float4*>(&red4[hc][1][0])[lane] = a1;
            reinterpret_cast<float4*>(&red4[hc][2][0])[lane] = a2;
            reinterpret_cast<float4*>(&red4[hc][3][0])[lane] = a3;
        }
        __syncthreads();

        // epilogue: wave = mention; sum 4 partials + bias, tanh, rank-5 proj
        {
            const int mi = wave;
            float4 dv = reinterpret_cast<const float4*>(bias)[lane];
            #pragma unroll
            for (int hc = 0; hc < HC; ++hc) {
                const float4 v = reinterpret_cast<const float4*>(&red4[hc][mi][0])[lane];
                dv.x += v.x; dv.y += v.y; dv.z += v.z; dv.w += v.w;
            }
            float v0 = tanhf(dv.x), v1 = tanhf(dv.y), v2 = tanhf(dv.z), v3 = tanhf(dv.w);

            int e0 = scoff + 4 * lane;
            float p[R];
            #pragma unroll
            for (int r = 0; r < R; ++r) {
                p[r] = v0 * Wsc[(size_t)(e0 + 0) * R + r] + v1 * Wsc[(size_t)(e0 + 1) * R + r]
                     + v2 * Wsc[(size_t)(e0 + 2) * R + r] + v3 * Wsc[(size_t)(e0 + 3) * R + r];
            }
            #pragma unroll
            for (int r = 0; r < R; ++r) {
                for (int off = 32; off; off >>= 1) p[r] += __shfl_down(p[r], off, 64);
            }
            if (lane == 0) {
                size_t rid = ((size_t)z * B + b) * M + mg * MT + mi;
                #pragma unroll
                for (int r = 0; r < R; ++r) sAB[rid * R + r] = p[r];
            }
        }
    } else if (blk < X_GEMM + X_SENT) {
        // sent partial max: block = (b, 2 z-chunks); z-chunk = 64 tokens
        int sb = blk - X_GEMM;
        int b = sb >> 4;
        int z = ((sb & 15) << 1) + (t >> 7);
        int tt = t & 127;   // float4 index over H
        const float4* p = reinterpret_cast<const float4*>(
            node + ((size_t)b * N + (size_t)z * NCHUNK) * H) + tt;
        float4 mx = p[0];
        #pragma unroll 8
        for (int n = 1; n < NCHUNK; ++n) {
            float4 v = p[(size_t)n * (H / 4)];
            mx.x = fmaxf(mx.x, v.x); mx.y = fmaxf(mx.y, v.y);
            mx.z = fmaxf(mx.z, v.z); mx.w = fmaxf(mx.w, v.w);
        }
        reinterpret_cast<float4*>(part + ((size_t)z * B + b) * H)[tt] = mx;
    } else {
        // distance table: 4 distances per block, one wave each
        int d = (blk - X_GEMM - X_SENT) * 4 + wave;
        float v = emb[(size_t)d * D + lane];
        #pragma unroll
        for (int r = 0; r < R; ++r) {
            float p = v * Wsc[(size_t)(2 * E + lane) * R + r];
            for (int off = 32; off; off >>= 1) p += __shfl_down(p, off, 64);
            if (lane == 0) sD[d * R + r] = p;
        }
    }
}

// ===========================================================================
// kY: per (b, 8-m tile): sent finish + sS in-block | pair max | atomicMax
// grid 96, block 256.
// ===========================================================================
__global__ __launch_bounds__(256)
void kY(const float* __restrict__ part, const float* __restrict__ Wsc,
        const float* __restrict__ bsc,
        const int* __restrict__ distance,
        const float* __restrict__ sAB, const float* __restrict__ validAB,
        const float* __restrict__ sD, float* __restrict__ out) {
    const int g = blockIdx.x % (M / MT4);
    const int b = blockIdx.x / (M / MT4);
    const int t = threadIdx.x;
    const int wave = t >> 6, lane = t & 63;

    __shared__ float sent[H];          // 2 KB
    __shared__ float red[R][4];
    __shared__ float sSb[R];
    __shared__ float lB[M * R];        // 1.9 KB
    __shared__ float lD[MAXD * R];     // 12 KB
    __shared__ float lA[MT4 * R];
    __shared__ float lvA[MT4], lvB[M];

    // sent max over NZ=32 partials (b-slice of part, L2-shared by 12 blocks)
    for (int h = t; h < H; h += 256) {
        float mx = -INFINITY;
        #pragma unroll 8
        for (int z = 0; z < NZ; ++z) mx = fmaxf(mx, part[((size_t)z * B + b) * H + h]);
        sent[h] = mx;
    }
    __syncthreads();

    // sS[r] = sent . Wsc[576:1088] + bsc
    {
        float acc[R] = {};
        for (int h = t; h < H; h += 256) {
            float v = sent[h];
            const float* w = Wsc + (size_t)(2 * E + D + h) * R;
            #pragma unroll
            for (int r = 0; r < R; ++r) acc[r] += v * w[r];
        }
        #pragma unroll
        for (int r = 0; r < R; ++r) {
            float v = acc[r];
            for (int off = 32; off; off >>= 1) v += __shfl_down(v, off, 64);
            if (lane == 0) red[r][wave] = v;
        }
        __syncthreads();
        if (t < R) sSb[t] = red[t][0] + red[t][1] + red[t][2] + red[t][3] + bsc[t];
        __syncthreads();
    }

    // stage tile operands
    for (int i = t; i < M * R; i += 256) lB[i] = sAB[((size_t)(B + b)) * M * R + i];
    for (int i = t; i < MAXD * R; i += 256) lD[i] = sD[i];
    if (t < MT4 * R) lA[t] = sAB[((size_t)b * M + g * MT4) * R + t] + sSb[t % R];
    if (t < MT4) lvA[t] = validAB[(size_t)b * M + g * MT4 + t];
    for (int i = t; i < M; i += 256) lvB[i] = validAB[((size_t)B + b) * M + i];
    __syncthreads();

    // pair max over 8 x 96
    float mx[R];
    #pragma unroll
    for (int r = 0; r < R; ++r) mx[r] = NEG_INF;

    #pragma unroll
    for (int it = 0; it < (MT4 * M) / 256; ++it) {
        int idx = it * 256 + t;           // [0, 768)
        int mi = idx / M, n = idx % M;
        int dist = distance[((size_t)b * M + g * MT4 + mi) * M + n];
        if (lvA[mi] > 0.f && lvB[n] > 0.f && dist >= 0 /*DIST_THRESH*/) {
            #pragma unroll
            for (int r = 0; r < R; ++r)
                mx[r] = fmaxf(mx[r], lA[mi * R + r] + lB[n * R + r] + lD[dist * R + r]);
        }
    }
    #pragma unroll
    for (int r = 0; r < R; ++r) {
        float v = mx[r];
        for (int off = 32; off; off >>= 1) v = fmaxf(v, __shfl_down(v, off, 64));
        if (lane == 0) red[r][wave] = v;
    }
    __syncthreads();
    if (t < R) {
        float v = fmaxf(fmaxf(red[t][0], red[t][1]), fmaxf(red[t][2], red[t][3]));
        atomicMaxFloat(out + b * R + t, v);
    }
}

// ---------------------------------------------------------------------------
extern "C" void kernel_launch(void* const* d_in, const int* in_sizes, int n_in,
                              void* d_out, int out_size, void* d_ws, size_t ws_size,
                              hipStream_t stream) {
    const float* node     = (const float*)d_in[0];
    const int*   cmap     = (const int*)  d_in[1];
    const float* cmask    = (const float*)d_in[2];
    const int*   dmap     = (const int*)  d_in[3];
    const float* dmask    = (const float*)d_in[4];
    const int*   distance = (const int*)  d_in[5];
    const float* Wc       = (const float*)d_in[6];
    const float* bc       = (const float*)d_in[7];
    const float* Wd       = (const float*)d_in[8];
    const float* bd       = (const float*)d_in[9];
    const float* Wsc      = (const float*)d_in[10];
    const float* bsc      = (const float*)d_in[11];
    const float* emb      = (const float*)d_in[12];
    float* out = (float*)d_out;

    // workspace layout (floats): total ~560 KB
    float* ws      = (float*)d_ws;
    float* part    = ws;                             // NZ*B*H   = 131072
    float* validAB = part + (size_t)NZ * B * H;      // 2*B*M    = 1536
    float* sD      = validAB + 2 * B * M;            // MAXD*R   = 3000
    float* sAB     = sD + MAXD * R;                  // 2*B*M*R  = 7680

    hipLaunchKernelGGL(kX, dim3(XG), dim3(256), 0, stream,
                       node, cmap, cmask, dmap, dmask, Wc, bc, Wd, bd, Wsc, emb,
                       part, sAB, validAB, sD, out);
    hipLaunchKernelGGL(kY, dim3((M / MT4) * B), dim3(256), 0, stream,
                       part, Wsc, bsc, distance, sAB, validAB, sD, out);
}